// Round 10
// baseline (123.879 us; speedup 1.0000x reference)
//
#include <hip/hip_runtime.h>
#include <cstdint>

#define BB   16
#define NN   1024
#define FIN  128
#define FOUT 64
#define ALPHA_S 0.2f

typedef float    f32x4 __attribute__((ext_vector_type(4)));
typedef int      i32x4 __attribute__((ext_vector_type(4)));
typedef _Float16 half8 __attribute__((ext_vector_type(8)));
typedef _Float16 half4 __attribute__((ext_vector_type(4)));

// ---------------------------------------------------------------------------
// Kernel 0: adj -> bitmask pack. Memcpy-shaped: 4096 blocks x 256 thr,
// ~28 VGPR -> 32 waves/CU; per wave 4 independent nontemporal dwordx4 loads
// (4 KB row), nibble + 3 shuffle-ORs (no ballot, no LDS), 128 B out/row.
// Mask layout: bit u of word (c*8+m) of row r  =  adj[r][c*256 + 32m + u].
// ---------------------------------------------------------------------------
__global__ __launch_bounds__(256) void k_pack(const int* __restrict__ adj,
                                              uint32_t* __restrict__ mask){
  const int t = threadIdx.x;
  const int w = t >> 6, lane = t & 63;
  const int grow = blockIdx.x * 4 + w;          // one row per wave
  const int* arow = adj + (size_t)grow * NN;

  uint32_t words[4];
  #pragma unroll
  for (int c = 0; c < 4; ++c){
    i32x4 v = __builtin_nontemporal_load((const i32x4*)(arow + c * 256 + lane * 4));
    uint32_t nib = (v[0] > 0 ? 1u : 0u) | (v[1] > 0 ? 2u : 0u)
                 | (v[2] > 0 ? 4u : 0u) | (v[3] > 0 ? 8u : 0u);
    uint32_t sh = nib << ((lane & 7) * 4);
    sh |= __shfl_xor(sh, 1, 64);
    sh |= __shfl_xor(sh, 2, 64);
    sh |= __shfl_xor(sh, 4, 64);                // lanes in each 8-group now equal
    words[c] = sh;
  }
  if ((lane & 7) == 0){
    const int m = lane >> 3;                    // 0..7
    #pragma unroll
    for (int c = 0; c < 4; ++c)
      mask[(size_t)grow * 32 + c * 8 + m] = words[c];
  }
}

// ---------------------------------------------------------------------------
// Kernel 1 (R6 form): h = inp @ W via f16 hi/lo MFMA; s1 = h.a1, s2 = h.a2;
// hT (f16 hi) in layout hT[b][j>>5][f][j&31].
// ---------------------------------------------------------------------------
__global__ __launch_bounds__(256) void k_proj(const float* __restrict__ inp,
                                              const float* __restrict__ W,
                                              const float* __restrict__ a,
                                              _Float16* __restrict__ hT,
                                              float* __restrict__ s1,
                                              float* __restrict__ s2){
  __shared__ float red1[4][16];
  __shared__ float red2[4][16];
  const int t = threadIdx.x;
  const int w = t >> 6, lane = t & 63;
  const int m16 = lane & 15, g = lane >> 4;
  const int i0 = blockIdx.x * 16;
  const int b  = i0 >> 10;
  const int j0 = i0 & 1023;
  const int c0 = w * 16;

  const float* arowf = inp + (size_t)(i0 + m16) * FIN;

  f32x4 acc = {0.f, 0.f, 0.f, 0.f};
  #pragma unroll
  for (int kk = 0; kk < 4; ++kk){
    const int kbase = kk * 32 + g * 8;
    float4 av0 = *(const float4*)(arowf + kbase);
    float4 av1 = *(const float4*)(arowf + kbase + 4);
    const float av[8] = {av0.x, av0.y, av0.z, av0.w, av1.x, av1.y, av1.z, av1.w};
    half8 ah, al;
    #pragma unroll
    for (int j = 0; j < 8; ++j){
      _Float16 h = (_Float16)av[j];
      ah[j] = h;
      al[j] = (_Float16)(av[j] - (float)h);
    }
    half8 bh, bl;
    #pragma unroll
    for (int j = 0; j < 8; ++j){
      float wv = W[(kbase + j) * FOUT + c0 + m16];     // L1-hot (W = 32 KB)
      _Float16 h = (_Float16)wv;
      bh[j] = h;
      bl[j] = (_Float16)(wv - (float)h);
    }
    acc = __builtin_amdgcn_mfma_f32_16x16x32_f16(ah, bh, acc, 0, 0, 0);
    acc = __builtin_amdgcn_mfma_f32_16x16x32_f16(ah, bl, acc, 0, 0, 0);
    acc = __builtin_amdgcn_mfma_f32_16x16x32_f16(al, bh, acc, 0, 0, 0);
  }

  const float a1c = a[c0 + m16];
  const float a2c = a[FOUT + c0 + m16];
  f32x4 p1, p2;
  #pragma unroll
  for (int q = 0; q < 4; ++q){ p1[q] = acc[q] * a1c; p2[q] = acc[q] * a2c; }
  #pragma unroll
  for (int off = 1; off < 16; off <<= 1){
    #pragma unroll
    for (int q = 0; q < 4; ++q){
      p1[q] += __shfl_xor(p1[q], off, 64);
      p2[q] += __shfl_xor(p2[q], off, 64);
    }
  }
  if (m16 == 0){
    #pragma unroll
    for (int q = 0; q < 4; ++q){
      red1[w][g * 4 + q] = p1[q];
      red2[w][g * 4 + q] = p2[q];
    }
  }

  half4 hv;
  #pragma unroll
  for (int q = 0; q < 4; ++q) hv[q] = (_Float16)acc[q];
  size_t idx = (size_t)b * 65536 + (size_t)(j0 >> 5) * 2048
             + (size_t)(c0 + m16) * 32 + (size_t)(j0 & 31) + (size_t)g * 4;
  *(half4*)(hT + idx) = hv;

  __syncthreads();
  if (t < 16){
    s1[i0 + t] = red1[0][t] + red1[1][t] + red1[2][t] + red1[3][t];
    s2[i0 + t] = red2[0][t] + red2[1][t] + red2[2][t] + red2[3][t];
  }
}

// ---------------------------------------------------------------------------
// Kernel 2 (unchanged from R9): masked-softmax + MFMA aggregation + ELU,
// reading 2 MB of bitmasks (32 B/lane) instead of adj.
// ---------------------------------------------------------------------------
__global__ __launch_bounds__(256) void k_attn(const uint32_t* __restrict__ mask,
                                              const _Float16* __restrict__ hT,
                                              const float* __restrict__ s1,
                                              const float* __restrict__ s2,
                                              float* __restrict__ out){
  __shared__ float s2_s[NN];            // 4 KB
  __shared__ float redmax[4][16];
  __shared__ float redl[4][16];
  __shared__ float csum[4][1088];       // ~17 KB

  const int t = threadIdx.x;
  const int w = t >> 6, lane = t & 63;
  const int m16 = lane & 15, g = lane >> 4;
  const int b  = blockIdx.x >> 6;
  const int i0 = (blockIdx.x & 63) * 16;
  const int jb = w * 256;

  *(float4*)&s2_s[jb + lane * 4] = *(const float4*)(s2 + b * NN + jb + lane * 4);

  const float s1i = s1[b * NN + i0 + m16];

  const uint32_t* mrow = mask + ((size_t)(b * NN + i0 + m16)) * 32 + w * 8;
  const uint4 mwa = *(const uint4*)mrow;
  const uint4 mwb = *(const uint4*)(mrow + 4);
  const uint32_t mw[8] = {mwa.x, mwa.y, mwa.z, mwa.w, mwb.x, mwb.y, mwb.z, mwb.w};

  float mxp = -3.0e38f;
  #pragma unroll
  for (int kk = 0; kk < 8; ++kk){
    float4 sA = *(const float4*)&s2_s[jb + kk * 32 + g * 8];
    float4 sB = *(const float4*)&s2_s[jb + kk * 32 + g * 8 + 4];
    const uint32_t bits8 = (mw[kk] >> (g * 8)) & 0xffu;
    const float sv[8] = {sA.x, sA.y, sA.z, sA.w, sB.x, sB.y, sB.z, sB.w};
    #pragma unroll
    for (int u = 0; u < 8; ++u)
      mxp = fmaxf(mxp, ((bits8 >> u) & 1u) ? sv[u] : -3.0e38f);
  }
  mxp = fmaxf(mxp, __shfl_xor(mxp, 16, 64));
  mxp = fmaxf(mxp, __shfl_xor(mxp, 32, 64));
  if (g == 0) redmax[w][m16] = mxp;
  __syncthreads();
  float mxg = fmaxf(fmaxf(redmax[0][m16], redmax[1][m16]),
                    fmaxf(redmax[2][m16], redmax[3][m16]));
  const bool empty = (mxg < -1.0e38f);
  const float xm = s1i + mxg;
  const float mrowmax = fmaxf(xm, ALPHA_S * xm);   // exact row max (monotone)

  f32x4 acc0 = {0,0,0,0}, acc1 = {0,0,0,0}, acc2 = {0,0,0,0}, acc3 = {0,0,0,0};
  float psum = 0.f;
  const _Float16* bhp = hT + (size_t)b * 65536 + (size_t)(jb >> 5) * 2048
                      + (size_t)m16 * 32 + (size_t)g * 8;

  #pragma unroll
  for (int kk = 0; kk < 8; ++kk){
    float4 sA = *(const float4*)&s2_s[jb + kk * 32 + g * 8];
    float4 sB = *(const float4*)&s2_s[jb + kk * 32 + g * 8 + 4];
    const uint32_t bits8 = (mw[kk] >> (g * 8)) & 0xffu;
    const float sv[8] = {sA.x, sA.y, sA.z, sA.w, sB.x, sB.y, sB.z, sB.w};
    half8 af;
    #pragma unroll
    for (int u = 0; u < 8; ++u){
      float x = s1i + sv[u];
      float e = fmaxf(x, ALPHA_S * x);
      float p = __expf(e - mrowmax);               // <= 1
      p = ((bits8 >> u) & 1u) ? p : 0.0f;
      p = empty ? 1.0f : p;                        // all-masked row -> uniform
      af[u] = (_Float16)p;
      psum += (float)af[u];                        // denom == numerator dtype
    }
    half8 b0 = *(const half8*)(bhp + kk * 2048);
    half8 b1 = *(const half8*)(bhp + kk * 2048 + 512);
    half8 b2 = *(const half8*)(bhp + kk * 2048 + 1024);
    half8 b3 = *(const half8*)(bhp + kk * 2048 + 1536);
    acc0 = __builtin_amdgcn_mfma_f32_16x16x32_f16(af, b0, acc0, 0, 0, 0);
    acc1 = __builtin_amdgcn_mfma_f32_16x16x32_f16(af, b1, acc1, 0, 0, 0);
    acc2 = __builtin_amdgcn_mfma_f32_16x16x32_f16(af, b2, acc2, 0, 0, 0);
    acc3 = __builtin_amdgcn_mfma_f32_16x16x32_f16(af, b3, acc3, 0, 0, 0);
  }

  psum += __shfl_xor(psum, 16, 64);
  psum += __shfl_xor(psum, 32, 64);
  if (g == 0) redl[w][m16] = psum;

  #pragma unroll
  for (int q = 0; q < 4; ++q){                     // C: row = g*4+q, col = c*16+m16
    csum[w][(g * 4 + q) * 68 +  0 + m16] = acc0[q];
    csum[w][(g * 4 + q) * 68 + 16 + m16] = acc1[q];
    csum[w][(g * 4 + q) * 68 + 32 + m16] = acc2[q];
    csum[w][(g * 4 + q) * 68 + 48 + m16] = acc3[q];
  }
  __syncthreads();

  const int r  = t >> 4;                           // 0..15
  const int c4 = (t & 15) * 4;                     // 0..60
  f32x4 sum = *(const f32x4*)&csum[0][r * 68 + c4];
  sum += *(const f32x4*)&csum[1][r * 68 + c4];
  sum += *(const f32x4*)&csum[2][r * 68 + c4];
  sum += *(const f32x4*)&csum[3][r * 68 + c4];
  const float linv = 1.0f / (redl[0][r] + redl[1][r] + redl[2][r] + redl[3][r]);
  f32x4 o;
  #pragma unroll
  for (int u = 0; u < 4; ++u){
    float v = sum[u] * linv;
    o[u] = v > 0.f ? v : __expf(v) - 1.0f;         // ELU (alpha=1)
  }
  *(f32x4*)(out + ((size_t)(b * NN + i0 + r)) * FOUT + c4) = o;
}

extern "C" void kernel_launch(void* const* d_in, const int* in_sizes, int n_in,
                              void* d_out, int out_size, void* d_ws, size_t ws_size,
                              hipStream_t stream) {
  (void)in_sizes; (void)n_in; (void)out_size; (void)ws_size;
  const float* inp = (const float*)d_in[0];   // (16,1024,128) fp32
  const int*   adj = (const int*)d_in[1];     // (16,1024,1024) int32
  const float* W   = (const float*)d_in[2];   // (128,64) fp32
  const float* a   = (const float*)d_in[3];   // (128,1) fp32
  float* outp = (float*)d_out;                // (16,1024,64) fp32

  _Float16* hT   = (_Float16*)d_ws;                    // 2 MB (hi only)
  float* s1      = (float*)(hT + (size_t)BB * 65536);  // 64 KB
  float* s2      = s1 + BB * NN;                       // 64 KB
  uint32_t* mask = (uint32_t*)(s2 + BB * NN);          // 2 MB

  k_pack<<<BB * NN / 4, 256, 0, stream>>>(adj, mask);
  k_proj<<<BB * NN / 16, 256, 0, stream>>>(inp, W, a, hT, s1, s2);
  k_attn<<<BB * (NN / 16), 256, 0, stream>>>(mask, hT, s1, s2, outp);
}

// Round 11
// 115.063 us; speedup vs baseline: 1.0766x; 1.0766x over previous
//
#include <hip/hip_runtime.h>
#include <cstdint>

#define BB   16
#define NN   1024
#define FIN  128
#define FOUT 64
#define ALPHA_S 0.2f

typedef float    f32x4 __attribute__((ext_vector_type(4)));
typedef _Float16 half8 __attribute__((ext_vector_type(8)));
typedef _Float16 half4 __attribute__((ext_vector_type(4)));

// ---------------------------------------------------------------------------
// Kernel 1: h = inp @ W via f16 hi/lo 3-term MFMA (rel err ~2^-22);
// s1 = h.a1, s2 = h.a2 (fp32); hT (f16 hi) in layout hT[b][j>>5][f][j&31].
// 1024 blocks x 256 thr; block = 16 rows; wave w = 16-col tile.
// ---------------------------------------------------------------------------
__global__ __launch_bounds__(256) void k_proj(const float* __restrict__ inp,
                                              const float* __restrict__ W,
                                              const float* __restrict__ a,
                                              _Float16* __restrict__ hT,
                                              float* __restrict__ s1,
                                              float* __restrict__ s2){
  __shared__ float red1[4][16];
  __shared__ float red2[4][16];
  const int t = threadIdx.x;
  const int w = t >> 6, lane = t & 63;
  const int m16 = lane & 15, g = lane >> 4;
  const int i0 = blockIdx.x * 16;
  const int b  = i0 >> 10;
  const int j0 = i0 & 1023;
  const int c0 = w * 16;

  const float* arow = inp + (size_t)(i0 + m16) * FIN;

  f32x4 acc = {0.f, 0.f, 0.f, 0.f};
  #pragma unroll
  for (int kk = 0; kk < 4; ++kk){
    const int kbase = kk * 32 + g * 8;
    float4 av0 = *(const float4*)(arow + kbase);
    float4 av1 = *(const float4*)(arow + kbase + 4);
    const float av[8] = {av0.x, av0.y, av0.z, av0.w, av1.x, av1.y, av1.z, av1.w};
    half8 ah, al;
    #pragma unroll
    for (int j = 0; j < 8; ++j){
      _Float16 h = (_Float16)av[j];
      ah[j] = h;
      al[j] = (_Float16)(av[j] - (float)h);
    }
    half8 bh, bl;
    #pragma unroll
    for (int j = 0; j < 8; ++j){
      float wv = W[(kbase + j) * FOUT + c0 + m16];   // L1-hot (W = 32 KB)
      _Float16 h = (_Float16)wv;
      bh[j] = h;
      bl[j] = (_Float16)(wv - (float)h);
    }
    acc = __builtin_amdgcn_mfma_f32_16x16x32_f16(ah, bh, acc, 0, 0, 0);
    acc = __builtin_amdgcn_mfma_f32_16x16x32_f16(ah, bl, acc, 0, 0, 0);
    acc = __builtin_amdgcn_mfma_f32_16x16x32_f16(al, bh, acc, 0, 0, 0);
  }

  const float a1c = a[c0 + m16];
  const float a2c = a[FOUT + c0 + m16];
  f32x4 p1, p2;
  #pragma unroll
  for (int q = 0; q < 4; ++q){ p1[q] = acc[q] * a1c; p2[q] = acc[q] * a2c; }
  #pragma unroll
  for (int off = 1; off < 16; off <<= 1){
    #pragma unroll
    for (int q = 0; q < 4; ++q){
      p1[q] += __shfl_xor(p1[q], off, 64);
      p2[q] += __shfl_xor(p2[q], off, 64);
    }
  }
  if (m16 == 0){
    #pragma unroll
    for (int q = 0; q < 4; ++q){
      red1[w][g * 4 + q] = p1[q];
      red2[w][g * 4 + q] = p2[q];
    }
  }

  half4 hv;
  #pragma unroll
  for (int q = 0; q < 4; ++q) hv[q] = (_Float16)acc[q];
  size_t idx = (size_t)b * 65536 + (size_t)(j0 >> 5) * 2048
             + (size_t)(c0 + m16) * 32 + (size_t)(j0 & 31) + (size_t)g * 4;
  *(half4*)(hT + idx) = hv;

  __syncthreads();
  if (t < 16){
    s1[i0 + t] = red1[0][t] + red1[1][t] + red1[2][t] + red1[3][t];
    s2[i0 + t] = red2[0][t] + red2[1][t] + red2[2][t] + red2[3][t];
  }
}

// ---------------------------------------------------------------------------
// Kernel 2: single-pass fused GAT attention (adj streamed in-kernel; the
// 64 MB adj read is the ~41 us umbrella that hides all attn compute).
// 1024 blocks x 256 thr. Block = (batch, 16-row tile). Wave w owns j-range
// [w*256, w*256+256) and all 64 output cols.
// Row max via monotonicity: m = leaky(s1_i + max_{adj} s2_j) from adj bits +
// s2 (4 KB LDS); p built directly in A-fragment layout (registers) -> MFMA.
// ---------------------------------------------------------------------------
__global__ __launch_bounds__(256) void k_attn(const int* __restrict__ adj,
                                              const _Float16* __restrict__ hT,
                                              const float* __restrict__ s1,
                                              const float* __restrict__ s2,
                                              float* __restrict__ out){
  __shared__ float s2_s[NN];            // 4 KB
  __shared__ float redmax[4][16];
  __shared__ float redl[4][16];
  __shared__ float csum[4][1088];       // ~17 KB

  const int t = threadIdx.x;
  const int w = t >> 6, lane = t & 63;
  const int m16 = lane & 15, g = lane >> 4;
  const int b  = blockIdx.x >> 6;
  const int i0 = (blockIdx.x & 63) * 16;
  const int jb = w * 256;

  // stage this wave's s2 quarter (wave-internal lgkmcnt ordering)
  *(float4*)&s2_s[jb + lane * 4] = *(const float4*)(s2 + b * NN + jb + lane * 4);

  const float s1i = s1[b * NN + i0 + m16];

  // ---- adj: 16 int4 loads in flight; row i0+m16, cols jb + kk*32 + g*8 ----
  const int* arow = adj + ((size_t)(b * NN + i0 + m16)) * NN + jb + g * 8;
  int4 A0[8], A1[8];
  #pragma unroll
  for (int kk = 0; kk < 8; ++kk){
    A0[kk] = *(const int4*)(arow + kk * 32);
    A1[kk] = *(const int4*)(arow + kk * 32 + 4);
  }

  // ---- bitmask + partial neighbor-max of s2 ----
  unsigned mask_lo = 0u, mask_hi = 0u;
  float mxp = -3.0e38f;
  #pragma unroll
  for (int kk = 0; kk < 8; ++kk){
    float4 sA = *(const float4*)&s2_s[jb + kk * 32 + g * 8];
    float4 sB = *(const float4*)&s2_s[jb + kk * 32 + g * 8 + 4];
    unsigned bits = 0u;
    bits |= (A0[kk].x > 0) ? 1u   : 0u;  mxp = fmaxf(mxp, A0[kk].x > 0 ? sA.x : -3.0e38f);
    bits |= (A0[kk].y > 0) ? 2u   : 0u;  mxp = fmaxf(mxp, A0[kk].y > 0 ? sA.y : -3.0e38f);
    bits |= (A0[kk].z > 0) ? 4u   : 0u;  mxp = fmaxf(mxp, A0[kk].z > 0 ? sA.z : -3.0e38f);
    bits |= (A0[kk].w > 0) ? 8u   : 0u;  mxp = fmaxf(mxp, A0[kk].w > 0 ? sA.w : -3.0e38f);
    bits |= (A1[kk].x > 0) ? 16u  : 0u;  mxp = fmaxf(mxp, A1[kk].x > 0 ? sB.x : -3.0e38f);
    bits |= (A1[kk].y > 0) ? 32u  : 0u;  mxp = fmaxf(mxp, A1[kk].y > 0 ? sB.y : -3.0e38f);
    bits |= (A1[kk].z > 0) ? 64u  : 0u;  mxp = fmaxf(mxp, A1[kk].z > 0 ? sB.z : -3.0e38f);
    bits |= (A1[kk].w > 0) ? 128u : 0u;  mxp = fmaxf(mxp, A1[kk].w > 0 ? sB.w : -3.0e38f);
    if (kk < 4) mask_lo |= bits << (kk * 8);
    else        mask_hi |= bits << ((kk - 4) * 8);
  }

  // row-max across the 4 g-lanes sharing m16, then across waves
  mxp = fmaxf(mxp, __shfl_xor(mxp, 16, 64));
  mxp = fmaxf(mxp, __shfl_xor(mxp, 32, 64));
  if (g == 0) redmax[w][m16] = mxp;
  __syncthreads();
  float mxg = fmaxf(fmaxf(redmax[0][m16], redmax[1][m16]),
                    fmaxf(redmax[2][m16], redmax[3][m16]));
  const bool empty = (mxg < -1.0e38f);
  const float xm = s1i + mxg;
  const float mrow = fmaxf(xm, ALPHA_S * xm);   // exact row max (monotone)

  // ---- Phase 2: p (A-frag, registers) -> 4 col-tile MFMAs (hi only) ----
  f32x4 acc0 = {0,0,0,0}, acc1 = {0,0,0,0}, acc2 = {0,0,0,0}, acc3 = {0,0,0,0};
  float psum = 0.f;
  const _Float16* bhp = hT + (size_t)b * 65536 + (size_t)(jb >> 5) * 2048
                      + (size_t)m16 * 32 + (size_t)g * 8;

  #pragma unroll
  for (int kk = 0; kk < 8; ++kk){
    float4 sA = *(const float4*)&s2_s[jb + kk * 32 + g * 8];
    float4 sB = *(const float4*)&s2_s[jb + kk * 32 + g * 8 + 4];
    const unsigned bits = (kk < 4) ? (mask_lo >> (kk * 8)) : (mask_hi >> ((kk - 4) * 8));
    const float sv[8] = {sA.x, sA.y, sA.z, sA.w, sB.x, sB.y, sB.z, sB.w};
    half8 af;
    #pragma unroll
    for (int u = 0; u < 8; ++u){
      float x = s1i + sv[u];
      float e = fmaxf(x, ALPHA_S * x);
      float p = __expf(e - mrow);                 // <= 1
      p = ((bits >> u) & 1u) ? p : 0.0f;
      p = empty ? 1.0f : p;                       // all-masked row -> uniform
      af[u] = (_Float16)p;
      psum += (float)af[u];                       // denom == numerator dtype
    }
    half8 b0 = *(const half8*)(bhp + kk * 2048);
    half8 b1 = *(const half8*)(bhp + kk * 2048 + 512);
    half8 b2 = *(const half8*)(bhp + kk * 2048 + 1024);
    half8 b3 = *(const half8*)(bhp + kk * 2048 + 1536);
    acc0 = __builtin_amdgcn_mfma_f32_16x16x32_f16(af, b0, acc0, 0, 0, 0);
    acc1 = __builtin_amdgcn_mfma_f32_16x16x32_f16(af, b1, acc1, 0, 0, 0);
    acc2 = __builtin_amdgcn_mfma_f32_16x16x32_f16(af, b2, acc2, 0, 0, 0);
    acc3 = __builtin_amdgcn_mfma_f32_16x16x32_f16(af, b3, acc3, 0, 0, 0);
  }

  // ---- epilogue: cross-wave l and C reduction, ELU, store ----
  psum += __shfl_xor(psum, 16, 64);
  psum += __shfl_xor(psum, 32, 64);
  if (g == 0) redl[w][m16] = psum;

  #pragma unroll
  for (int q = 0; q < 4; ++q){                   // C: row = g*4+q, col = c*16+m16
    csum[w][(g * 4 + q) * 68 +  0 + m16] = acc0[q];
    csum[w][(g * 4 + q) * 68 + 16 + m16] = acc1[q];
    csum[w][(g * 4 + q) * 68 + 32 + m16] = acc2[q];
    csum[w][(g * 4 + q) * 68 + 48 + m16] = acc3[q];
  }
  __syncthreads();

  const int r  = t >> 4;                         // 0..15
  const int c4 = (t & 15) * 4;                   // 0..60
  f32x4 sum = *(const f32x4*)&csum[0][r * 68 + c4];
  sum += *(const f32x4*)&csum[1][r * 68 + c4];
  sum += *(const f32x4*)&csum[2][r * 68 + c4];
  sum += *(const f32x4*)&csum[3][r * 68 + c4];
  const float linv = 1.0f / (redl[0][r] + redl[1][r] + redl[2][r] + redl[3][r]);
  f32x4 o;
  #pragma unroll
  for (int u = 0; u < 4; ++u){
    float v = sum[u] * linv;
    o[u] = v > 0.f ? v : __expf(v) - 1.0f;       // ELU (alpha=1)
  }
  *(f32x4*)(out + ((size_t)(b * NN + i0 + r)) * FOUT + c4) = o;
}

extern "C" void kernel_launch(void* const* d_in, const int* in_sizes, int n_in,
                              void* d_out, int out_size, void* d_ws, size_t ws_size,
                              hipStream_t stream) {
  (void)in_sizes; (void)n_in; (void)out_size; (void)ws_size;
  const float* inp = (const float*)d_in[0];   // (16,1024,128) fp32
  const int*   adj = (const int*)d_in[1];     // (16,1024,1024) int32
  const float* W   = (const float*)d_in[2];   // (128,64) fp32
  const float* a   = (const float*)d_in[3];   // (128,1) fp32
  float* outp = (float*)d_out;                // (16,1024,64) fp32

  _Float16* hT = (_Float16*)d_ws;                      // 2 MB (hi only)
  float* s1 = (float*)(hT + (size_t)BB * 65536);       // 64 KB
  float* s2 = s1 + BB * NN;                            // 64 KB

  k_proj<<<BB * NN / 16, 256, 0, stream>>>(inp, W, a, hT, s1, s2);
  k_attn<<<BB * (NN / 16), 256, 0, stream>>>(adj, hT, s1, s2, outp);
}